// Round 1
// baseline (717.026 us; speedup 1.0000x reference)
//
#include <hip/hip_runtime.h>
#include <stdint.h>

#define SQL 2048
#define HID 4096
#define NHEADS 32
#define HDSZ 128
#define QKVD 4608
#define QDIM 4096

typedef unsigned short u16;
typedef __attribute__((ext_vector_type(8))) short short8;
typedef __attribute__((ext_vector_type(4))) float f32x4;

#define AS1(p) ((__attribute__((address_space(1))) void*)(p))
#define AS3(p) ((__attribute__((address_space(3))) void*)(p))

__device__ __forceinline__ float bf2f(u16 u) {
  return __uint_as_float(((uint32_t)u) << 16);
}
__device__ __forceinline__ u16 f2bf(float f) {
  uint32_t x = __float_as_uint(f);
  x += 0x7fffu + ((x >> 16) & 1u);
  return (u16)(x >> 16);
}

// ---------- fp32 -> bf16 convert, 8 elems/thread ----------
__global__ void k_cvt(const float* __restrict__ in, u16* __restrict__ out, int n8) {
  int i = blockIdx.x * blockDim.x + threadIdx.x;
  int stride = gridDim.x * blockDim.x;
  for (; i < n8; i += stride) {
    const float4* p = reinterpret_cast<const float4*>(in) + (size_t)i * 2;
    float4 a = p[0], b = p[1];
    short8 o;
    o[0] = (short)f2bf(a.x); o[1] = (short)f2bf(a.y);
    o[2] = (short)f2bf(a.z); o[3] = (short)f2bf(a.w);
    o[4] = (short)f2bf(b.x); o[5] = (short)f2bf(b.y);
    o[6] = (short)f2bf(b.z); o[7] = (short)f2bf(b.w);
    reinterpret_cast<short8*>(out)[i] = o;
  }
}

// ---------- GEMM C[M][N] = A[M][K] * B[N][K]^T, bf16 MFMA ----------
// MODE 0: qkv epilogue (bias + scatter to q/k/vt).  MODE 1: fp32 C store.
template<int MODE>
__global__ __launch_bounds__(256, 2)
void k_gemm(const u16* __restrict__ A, const u16* __restrict__ B,
            const float* __restrict__ bias,
            u16* __restrict__ qbuf, u16* __restrict__ kbuf, u16* __restrict__ vtbuf,
            float* __restrict__ outf)
{
  __shared__ __align__(16) u16 ldsA[128 * 64];
  __shared__ __align__(16) u16 ldsB[128 * 64];
  const int tid = threadIdx.x;
  const int wid = tid >> 6, lane = tid & 63;
  const int l15 = lane & 15, lg = lane >> 4;
  const int m0 = blockIdx.y * 128, n0 = blockIdx.x * 128;
  const int wr = wid >> 1, wc = wid & 1;

  f32x4 acc[4][4] = {};

  // staging geometry: wave covers 1KB segments; LDS row = 128B (64 bf16).
  // LDS[row][kb] holds global A[row][kb ^ ((row&7)<<4)]  (T2 swizzle, rule #21:
  // linear LDS dest + inverse-swizzled global source).
  const int srow = lane >> 3;                      // row within 8-row segment
  const int skb  = (((lane & 7) ^ srow) << 4);     // pre-swizzled source byte
  const size_t rowbytes = (size_t)HID * 2;

  for (int t = 0; t < HID / 64; ++t) {
    __syncthreads();
    const char* Ab = (const char*)A + (size_t)m0 * rowbytes + (size_t)t * 128;
    const char* Bb = (const char*)B + (size_t)n0 * rowbytes + (size_t)t * 128;
#pragma unroll
    for (int i = 0; i < 4; ++i) {
      int seg = i * 4 + wid;
      int row = seg * 8 + srow;
      __builtin_amdgcn_global_load_lds(AS1(Ab + (size_t)row * rowbytes + skb),
                                       AS3(ldsA + seg * 512), 16, 0, 0);
      __builtin_amdgcn_global_load_lds(AS1(Bb + (size_t)row * rowbytes + skb),
                                       AS3(ldsB + seg * 512), 16, 0, 0);
    }
    __syncthreads();
#pragma unroll
    for (int kc = 0; kc < 2; ++kc) {
      short8 af[4], bfr[4];
#pragma unroll
      for (int mi = 0; mi < 4; ++mi) {
        int row = wr * 64 + mi * 16 + l15;
        int kb = (kc * 64 + lg * 16) ^ ((row & 7) << 4);
        af[mi] = *reinterpret_cast<const short8*>((const char*)ldsA + row * 128 + kb);
      }
#pragma unroll
      for (int ni = 0; ni < 4; ++ni) {
        int row = wc * 64 + ni * 16 + l15;
        int kb = (kc * 64 + lg * 16) ^ ((row & 7) << 4);
        bfr[ni] = *reinterpret_cast<const short8*>((const char*)ldsB + row * 128 + kb);
      }
#pragma unroll
      for (int mi = 0; mi < 4; ++mi)
#pragma unroll
        for (int ni = 0; ni < 4; ++ni)
          acc[mi][ni] = __builtin_amdgcn_mfma_f32_16x16x32_bf16(af[mi], bfr[ni], acc[mi][ni], 0, 0, 0);
    }
  }

  // epilogue: C row = m0 + wr*64 + mi*16 + (lane>>4)*4 + j ; col = n0 + wc*64 + ni*16 + (lane&15)
#pragma unroll
  for (int mi = 0; mi < 4; ++mi) {
#pragma unroll
    for (int ni = 0; ni < 4; ++ni) {
      int row0 = m0 + wr * 64 + mi * 16 + lg * 4;
      int col  = n0 + wc * 64 + ni * 16 + l15;
      if (MODE == 0) {
        float bv = bias[col];
#pragma unroll
        for (int j = 0; j < 4; ++j) {
          float v = acc[mi][ni][j] + bv;
          u16 hb = f2bf(v);
          int r = row0 + j;
          if (col < QDIM) {
            int hh = col >> 7, d = col & 127;
            qbuf[((size_t)hh * SQL + r) * HDSZ + d] = hb;
          } else if (col < QDIM + 256) {
            int c2 = col - QDIM; int g = c2 >> 7, d = c2 & 127;
            kbuf[((size_t)g * SQL + r) * HDSZ + d] = hb;
          } else {
            int c2 = col - QDIM - 256; int g = c2 >> 7, d = c2 & 127;
            vtbuf[((size_t)g * HDSZ + d) * SQL + r] = hb;   // V stored transposed
          }
        }
      } else {
#pragma unroll
        for (int j = 0; j < 4; ++j)
          outf[(size_t)(row0 + j) * QDIM + col] = acc[mi][ni][j];
      }
    }
  }
}

// ---------- RoPE (interleaved pairs, first 64 dims), in place on q and k ----------
__global__ void k_rope(u16* __restrict__ qbuf, u16* __restrict__ kbuf,
                       const float* __restrict__ rope) {
  int idx = blockIdx.x * blockDim.x + threadIdx.x;
  if (idx >= SQL * 34 * 32) return;
  int p = idx & 31;
  int hh = (idx >> 5) % 34;
  int s = idx / (34 * 32);
  float c  = rope[s * 64 + p * 2 + 0];
  float sn = rope[s * 64 + p * 2 + 1];
  u16* base = (hh < 32) ? (qbuf + ((size_t)hh * SQL + s) * HDSZ)
                        : (kbuf + ((size_t)(hh - 32) * SQL + s) * HDSZ);
  u16* pp = base + 2 * p;
  uint32_t packed = *reinterpret_cast<uint32_t*>(pp);
  float x0 = bf2f((u16)(packed & 0xffff));
  float x1 = bf2f((u16)(packed >> 16));
  float o0 = x0 * c - x1 * sn;
  float o1 = x1 * c + x0 * sn;
  *reinterpret_cast<uint32_t*>(pp) = (uint32_t)f2bf(o0) | ((uint32_t)f2bf(o1) << 16);
}

// ---------- flash attention: causal, GQA (g = h>>4), online softmax ----------
// 4 waves/block, 16 q-rows per wave, KV tiles of 32. Waves fully independent
// (per-wave causal loop bound -> no block barriers in divergent loop).
__global__ __launch_bounds__(256, 2)
void k_attn(const u16* __restrict__ qbuf, const u16* __restrict__ kbuf,
            const u16* __restrict__ vtbuf, u16* __restrict__ ctx)
{
  __shared__ __align__(16) u16 pls[4][16 * 40];   // per-wave P tile, padded (+8 bf16)
  const int tid = threadIdx.x;
  const int wid = tid >> 6, lane = tid & 63;
  const int l15 = lane & 15, lg = lane >> 4;
  const int h = blockIdx.y;
  const int g = h >> 4;                     // n_rep = 16
  const int q0 = blockIdx.x * 64 + wid * 16;
  const float inv_norm = 0.08838834764831845f;   // 1/sqrt(128)

  short8 aq[4];
  {
    const u16* qp = qbuf + ((size_t)h * SQL + q0 + l15) * HDSZ + lg * 8;
#pragma unroll
    for (int kc = 0; kc < 4; ++kc)
      aq[kc] = *reinterpret_cast<const short8*>(qp + kc * 32);
  }
  f32x4 o[8] = {};
  float mrow[4], lrow[4];
#pragma unroll
  for (int j = 0; j < 4; ++j) { mrow[j] = -__builtin_inff(); lrow[j] = 0.f; }

  const int jend = q0 + 15;                 // last visible kv for this wave
  for (int j0 = 0; j0 <= jend; j0 += 32) {
    short8 bk[2][4];
    const u16* kp = kbuf + ((size_t)g * SQL + j0 + l15) * HDSZ + lg * 8;
#pragma unroll
    for (int cf = 0; cf < 2; ++cf)
#pragma unroll
      for (int kc = 0; kc < 4; ++kc)
        bk[cf][kc] = *reinterpret_cast<const short8*>(kp + cf * 16 * HDSZ + kc * 32);
    short8 bv[8];
    const u16* vp = vtbuf + ((size_t)g * HDSZ + l15) * SQL + j0 + lg * 8;
#pragma unroll
    for (int df = 0; df < 8; ++df)
      bv[df] = *reinterpret_cast<const short8*>(vp + (size_t)df * 16 * SQL);

    f32x4 s0 = {}, s1 = {};
#pragma unroll
    for (int kc = 0; kc < 4; ++kc) {
      s0 = __builtin_amdgcn_mfma_f32_16x16x32_bf16(aq[kc], bk[0][kc], s0, 0, 0, 0);
      s1 = __builtin_amdgcn_mfma_f32_16x16x32_bf16(aq[kc], bk[1][kc], s1, 0, 0, 0);
    }

    float al[4];
#pragma unroll
    for (int j = 0; j < 4; ++j) {
      int row = q0 + lg * 4 + j;
      float v0 = s0[j] * inv_norm;
      float v1 = s1[j] * inv_norm;
      if (j0 + l15 > row)      v0 = -1e30f;
      if (j0 + 16 + l15 > row) v1 = -1e30f;
      float rm = fmaxf(v0, v1);
      rm = fmaxf(rm, __shfl_xor(rm, 1));
      rm = fmaxf(rm, __shfl_xor(rm, 2));
      rm = fmaxf(rm, __shfl_xor(rm, 4));
      rm = fmaxf(rm, __shfl_xor(rm, 8));
      float mn = fmaxf(mrow[j], rm);
      float a = __expf(mrow[j] - mn);       // first tile: exp(-inf)=0
      mrow[j] = mn;
      float p0 = __expf(v0 - mn);
      float p1 = __expf(v1 - mn);
      float ps = p0 + p1;
      ps += __shfl_xor(ps, 1);
      ps += __shfl_xor(ps, 2);
      ps += __shfl_xor(ps, 4);
      ps += __shfl_xor(ps, 8);
      lrow[j] = lrow[j] * a + ps;
      al[j] = a;
      int rl = lg * 4 + j;
      pls[wid][rl * 40 + l15]      = f2bf(p0);
      pls[wid][rl * 40 + 16 + l15] = f2bf(p1);
    }
    asm volatile("s_waitcnt lgkmcnt(0)" ::: "memory");  // wave-local P write->read
    short8 ap = *reinterpret_cast<const short8*>(&pls[wid][l15 * 40 + lg * 8]);
#pragma unroll
    for (int df = 0; df < 8; ++df) {
      f32x4 t = o[df];
      t[0] *= al[0]; t[1] *= al[1]; t[2] *= al[2]; t[3] *= al[3];
      o[df] = __builtin_amdgcn_mfma_f32_16x16x32_bf16(ap, bv[df], t, 0, 0, 0);
    }
  }

#pragma unroll
  for (int j = 0; j < 4; ++j) {
    float inv_l = 1.0f / lrow[j];
    int row = q0 + lg * 4 + j;
    u16* cp = ctx + (size_t)row * QDIM + h * HDSZ;
#pragma unroll
    for (int df = 0; df < 8; ++df)
      cp[df * 16 + l15] = f2bf(o[df][j] * inv_l);
  }
}

// ---------- workspace layout (bytes) ----------
//  0        : hidden_bf16 [2048][4096]   16777216   (reused as ctx after GEMM1)
//  16777216 : W_bf16      [4608][4096]   37748736   (Wqkv, then Wdense)
//  54525952 : q           [32][2048][128] 16777216
//  71303168 : k           [2][2048][128]   1048576
//  72351744 : vt          [2][128][2048]   1048576
//  total 73400320

extern "C" void kernel_launch(void* const* d_in, const int* in_sizes, int n_in,
                              void* d_out, int out_size, void* d_ws, size_t ws_size,
                              hipStream_t stream) {
  const float* hs     = (const float*)d_in[0];
  const float* wqkv   = (const float*)d_in[1];
  const float* bqkv   = (const float*)d_in[2];
  const float* wdense = (const float*)d_in[3];
  const float* rope   = (const float*)d_in[4];
  char* ws = (char*)d_ws;
  u16* hid_b = (u16*)(ws + 0);
  u16* w_b   = (u16*)(ws + 16777216);
  u16* qb    = (u16*)(ws + 54525952);
  u16* kb    = (u16*)(ws + 71303168);
  u16* vtb   = (u16*)(ws + 72351744);
  u16* ctx   = hid_b;                      // reuse after GEMM1
  float* outf = (float*)d_out;

  k_cvt<<<2048, 256, 0, stream>>>(hs,   hid_b, SQL * HID / 8);
  k_cvt<<<2048, 256, 0, stream>>>(wqkv, w_b,   QKVD * HID / 8);
  k_gemm<0><<<dim3(QKVD / 128, SQL / 128), 256, 0, stream>>>(
      hid_b, w_b, bqkv, qb, kb, vtb, nullptr);
  k_rope<<<(SQL * 34 * 32) / 256, 256, 0, stream>>>(qb, kb, rope);
  k_cvt<<<2048, 256, 0, stream>>>(wdense, w_b, QDIM * HID / 8);   // after GEMM1
  k_attn<<<dim3(SQL / 64, NHEADS), 256, 0, stream>>>(qb, kb, vtb, ctx);
  k_gemm<1><<<dim3(QDIM / 128, SQL / 128), 256, 0, stream>>>(
      ctx, w_b, nullptr, nullptr, nullptr, nullptr, outf);
}

// Round 3
// 454.898 us; speedup vs baseline: 1.5762x; 1.5762x over previous
//
#include <hip/hip_runtime.h>
#include <stdint.h>

#define SQL 2048
#define HID 4096
#define NHEADS 32
#define HDSZ 128
#define QKVD 4608
#define QDIM 4096

typedef unsigned short u16;
typedef __attribute__((ext_vector_type(8))) short short8;
typedef __attribute__((ext_vector_type(4))) float f32x4;

#define AS1(p) ((__attribute__((address_space(1))) void*)(p))
#define AS3(p) ((__attribute__((address_space(3))) void*)(p))

__device__ __forceinline__ float bf2f(u16 u) {
  return __uint_as_float(((uint32_t)u) << 16);
}
__device__ __forceinline__ u16 f2bf(float f) {
  uint32_t x = __float_as_uint(f);
  x += 0x7fffu + ((x >> 16) & 1u);
  return (u16)(x >> 16);
}

// ---------- fp32 -> bf16 convert, 8 elems/thread ----------
__global__ void k_cvt(const float* __restrict__ in, u16* __restrict__ out, int n8) {
  int i = blockIdx.x * blockDim.x + threadIdx.x;
  int stride = gridDim.x * blockDim.x;
  for (; i < n8; i += stride) {
    const float4* p = reinterpret_cast<const float4*>(in) + (size_t)i * 2;
    float4 a = p[0], b = p[1];
    short8 o;
    o[0] = (short)f2bf(a.x); o[1] = (short)f2bf(a.y);
    o[2] = (short)f2bf(a.z); o[3] = (short)f2bf(a.w);
    o[4] = (short)f2bf(b.x); o[5] = (short)f2bf(b.y);
    o[6] = (short)f2bf(b.z); o[7] = (short)f2bf(b.w);
    reinterpret_cast<short8*>(out)[i] = o;
  }
}

// ---------- GEMM C[M][N] = A[M][K] * B[N][K]^T, bf16 MFMA ----------
// MODE 0: qkv epilogue (bias + scatter to q/k/vt).  MODE 1: fp32 C store.
template<int MODE>
__global__ __launch_bounds__(256, 2)
void k_gemm(const u16* __restrict__ A, const u16* __restrict__ B,
            const float* __restrict__ bias,
            u16* __restrict__ qbuf, u16* __restrict__ kbuf, u16* __restrict__ vtbuf,
            float* __restrict__ outf)
{
  __shared__ __align__(16) u16 ldsA[128 * 64];
  __shared__ __align__(16) u16 ldsB[128 * 64];
  const int tid = threadIdx.x;
  const int wid = tid >> 6, lane = tid & 63;
  const int l15 = lane & 15, lg = lane >> 4;
  const int m0 = blockIdx.y * 128, n0 = blockIdx.x * 128;
  const int wr = wid >> 1, wc = wid & 1;

  f32x4 acc[4][4] = {};

  // staging geometry: wave covers 1KB segments; LDS row = 128B (64 bf16).
  // LDS[row][kb] holds global A[row][kb ^ ((row&7)<<4)]  (T2 swizzle, rule #21:
  // linear LDS dest + inverse-swizzled global source).
  const int srow = lane >> 3;                      // row within 8-row segment
  const int skb  = (((lane & 7) ^ srow) << 4);     // pre-swizzled source byte
  const size_t rowbytes = (size_t)HID * 2;

  for (int t = 0; t < HID / 64; ++t) {
    __syncthreads();
    const char* Ab = (const char*)A + (size_t)m0 * rowbytes + (size_t)t * 128;
    const char* Bb = (const char*)B + (size_t)n0 * rowbytes + (size_t)t * 128;
#pragma unroll
    for (int i = 0; i < 4; ++i) {
      int seg = i * 4 + wid;
      int row = seg * 8 + srow;
      __builtin_amdgcn_global_load_lds(AS1(Ab + (size_t)row * rowbytes + skb),
                                       AS3(ldsA + seg * 512), 16, 0, 0);
      __builtin_amdgcn_global_load_lds(AS1(Bb + (size_t)row * rowbytes + skb),
                                       AS3(ldsB + seg * 512), 16, 0, 0);
    }
    __syncthreads();
#pragma unroll
    for (int kc = 0; kc < 2; ++kc) {
      short8 af[4], bfr[4];
#pragma unroll
      for (int mi = 0; mi < 4; ++mi) {
        int row = wr * 64 + mi * 16 + l15;
        int kb = (kc * 64 + lg * 16) ^ ((row & 7) << 4);
        af[mi] = *reinterpret_cast<const short8*>((const char*)ldsA + row * 128 + kb);
      }
#pragma unroll
      for (int ni = 0; ni < 4; ++ni) {
        int row = wc * 64 + ni * 16 + l15;
        int kb = (kc * 64 + lg * 16) ^ ((row & 7) << 4);
        bfr[ni] = *reinterpret_cast<const short8*>((const char*)ldsB + row * 128 + kb);
      }
#pragma unroll
      for (int mi = 0; mi < 4; ++mi)
#pragma unroll
        for (int ni = 0; ni < 4; ++ni)
          acc[mi][ni] = __builtin_amdgcn_mfma_f32_16x16x32_bf16(af[mi], bfr[ni], acc[mi][ni], 0, 0, 0);
    }
  }

  // epilogue: C row = m0 + wr*64 + mi*16 + (lane>>4)*4 + j ; col = n0 + wc*64 + ni*16 + (lane&15)
#pragma unroll
  for (int mi = 0; mi < 4; ++mi) {
#pragma unroll
    for (int ni = 0; ni < 4; ++ni) {
      int row0 = m0 + wr * 64 + mi * 16 + lg * 4;
      int col  = n0 + wc * 64 + ni * 16 + l15;
      if (MODE == 0) {
        float bv = bias[col];
#pragma unroll
        for (int j = 0; j < 4; ++j) {
          float v = acc[mi][ni][j] + bv;
          u16 hb = f2bf(v);
          int r = row0 + j;
          if (col < QDIM) {
            int hh = col >> 7, d = col & 127;
            qbuf[((size_t)hh * SQL + r) * HDSZ + d] = hb;
          } else if (col < QDIM + 256) {
            int c2 = col - QDIM; int g = c2 >> 7, d = c2 & 127;
            kbuf[((size_t)g * SQL + r) * HDSZ + d] = hb;
          } else {
            int c2 = col - QDIM - 256; int g = c2 >> 7, d = c2 & 127;
            vtbuf[((size_t)g * HDSZ + d) * SQL + r] = hb;   // V stored transposed
          }
        }
      } else {
#pragma unroll
        for (int j = 0; j < 4; ++j)
          outf[(size_t)(row0 + j) * QDIM + col] = acc[mi][ni][j];
      }
    }
  }
}

// ---------- RoPE (interleaved pairs, first 64 dims), in place on q and k ----------
__global__ void k_rope(u16* __restrict__ qbuf, u16* __restrict__ kbuf,
                       const float* __restrict__ rope) {
  int idx = blockIdx.x * blockDim.x + threadIdx.x;
  if (idx >= SQL * 34 * 32) return;
  int p = idx & 31;
  int hh = (idx >> 5) % 34;
  int s = idx / (34 * 32);
  float c  = rope[s * 64 + p * 2 + 0];
  float sn = rope[s * 64 + p * 2 + 1];
  u16* base = (hh < 32) ? (qbuf + ((size_t)hh * SQL + s) * HDSZ)
                        : (kbuf + ((size_t)(hh - 32) * SQL + s) * HDSZ);
  u16* pp = base + 2 * p;
  uint32_t packed = *reinterpret_cast<uint32_t*>(pp);
  float x0 = bf2f((u16)(packed & 0xffff));
  float x1 = bf2f((u16)(packed >> 16));
  float o0 = x0 * c - x1 * sn;
  float o1 = x1 * c + x0 * sn;
  *reinterpret_cast<uint32_t*>(pp) = (uint32_t)f2bf(o0) | ((uint32_t)f2bf(o1) << 16);
}

// ---------- flash attention: causal, GQA (g = h>>4), online softmax ----------
// ONE wave per block, 16 q-rows per wave, KV tiles of 32.
// grid = (NHEADS, SQL/16); qi = 127 - blockIdx.y  => heaviest blocks (largest
// causal extent) dispatch first across ALL heads (global LPT ordering), and
// 64-thread workgroups let ~16 wg/CU stay resident -> ~4 waves/SIMD of TLP.
__global__ __launch_bounds__(64, 4)
void k_attn(const u16* __restrict__ qbuf, const u16* __restrict__ kbuf,
            const u16* __restrict__ vtbuf, u16* __restrict__ ctx)
{
  __shared__ __align__(16) u16 pls[16 * 40];   // P tile, padded (+8 bf16)
  const int lane = threadIdx.x;
  const int l15 = lane & 15, lg = lane >> 4;
  const int h = blockIdx.x;
  const int g = h >> 4;                     // n_rep = 16
  const int qi = (int)gridDim.y - 1 - (int)blockIdx.y;
  const int q0 = qi * 16;
  const float inv_norm = 0.08838834764831845f;   // 1/sqrt(128)

  short8 aq[4];
  {
    const u16* qp = qbuf + ((size_t)h * SQL + q0 + l15) * HDSZ + lg * 8;
#pragma unroll
    for (int kc = 0; kc < 4; ++kc)
      aq[kc] = *reinterpret_cast<const short8*>(qp + kc * 32);
  }
  f32x4 o[8] = {};
  float mrow[4], lrow[4];
#pragma unroll
  for (int j = 0; j < 4; ++j) { mrow[j] = -__builtin_inff(); lrow[j] = 0.f; }

  const int jend = q0 + 15;                 // last visible kv for this wave
  for (int j0 = 0; j0 <= jend; j0 += 32) {
    short8 bk[2][4];
    const u16* kp = kbuf + ((size_t)g * SQL + j0 + l15) * HDSZ + lg * 8;
#pragma unroll
    for (int cf = 0; cf < 2; ++cf)
#pragma unroll
      for (int kc = 0; kc < 4; ++kc)
        bk[cf][kc] = *reinterpret_cast<const short8*>(kp + cf * 16 * HDSZ + kc * 32);
    short8 bv[8];
    const u16* vp = vtbuf + ((size_t)g * HDSZ + l15) * SQL + j0 + lg * 8;
#pragma unroll
    for (int df = 0; df < 8; ++df)
      bv[df] = *reinterpret_cast<const short8*>(vp + (size_t)df * 16 * SQL);

    f32x4 s0 = {}, s1 = {};
#pragma unroll
    for (int kc = 0; kc < 4; ++kc) {
      s0 = __builtin_amdgcn_mfma_f32_16x16x32_bf16(aq[kc], bk[0][kc], s0, 0, 0, 0);
      s1 = __builtin_amdgcn_mfma_f32_16x16x32_bf16(aq[kc], bk[1][kc], s1, 0, 0, 0);
    }

    float al[4];
#pragma unroll
    for (int j = 0; j < 4; ++j) {
      int row = q0 + lg * 4 + j;
      float v0 = s0[j] * inv_norm;
      float v1 = s1[j] * inv_norm;
      if (j0 + l15 > row)      v0 = -1e30f;
      if (j0 + 16 + l15 > row) v1 = -1e30f;
      float rm = fmaxf(v0, v1);
      rm = fmaxf(rm, __shfl_xor(rm, 1));
      rm = fmaxf(rm, __shfl_xor(rm, 2));
      rm = fmaxf(rm, __shfl_xor(rm, 4));
      rm = fmaxf(rm, __shfl_xor(rm, 8));
      float mn = fmaxf(mrow[j], rm);
      float a = __expf(mrow[j] - mn);       // first tile: exp(-inf)=0
      mrow[j] = mn;
      float p0 = __expf(v0 - mn);
      float p1 = __expf(v1 - mn);
      float ps = p0 + p1;
      ps += __shfl_xor(ps, 1);
      ps += __shfl_xor(ps, 2);
      ps += __shfl_xor(ps, 4);
      ps += __shfl_xor(ps, 8);
      lrow[j] = lrow[j] * a + ps;
      al[j] = a;
      int rl = lg * 4 + j;
      pls[rl * 40 + l15]      = f2bf(p0);
      pls[rl * 40 + 16 + l15] = f2bf(p1);
    }
    asm volatile("s_waitcnt lgkmcnt(0)" ::: "memory");  // wave-local P write->read
    short8 ap = *reinterpret_cast<const short8*>(&pls[l15 * 40 + lg * 8]);
#pragma unroll
    for (int df = 0; df < 8; ++df) {
      f32x4 t = o[df];
      t[0] *= al[0]; t[1] *= al[1]; t[2] *= al[2]; t[3] *= al[3];
      o[df] = __builtin_amdgcn_mfma_f32_16x16x32_bf16(ap, bv[df], t, 0, 0, 0);
    }
  }

#pragma unroll
  for (int j = 0; j < 4; ++j) {
    float inv_l = 1.0f / lrow[j];
    int row = q0 + lg * 4 + j;
    u16* cp = ctx + (size_t)row * QDIM + h * HDSZ;
#pragma unroll
    for (int df = 0; df < 8; ++df)
      cp[df * 16 + l15] = f2bf(o[df][j] * inv_l);
  }
}

// ---------- workspace layout (bytes) ----------
//  0        : hidden_bf16 [2048][4096]   16777216   (reused as ctx after GEMM1)
//  16777216 : W_bf16      [4608][4096]   37748736   (Wqkv, then Wdense)
//  54525952 : q           [32][2048][128] 16777216
//  71303168 : k           [2][2048][128]   1048576
//  72351744 : vt          [2][128][2048]   1048576
//  total 73400320

extern "C" void kernel_launch(void* const* d_in, const int* in_sizes, int n_in,
                              void* d_out, int out_size, void* d_ws, size_t ws_size,
                              hipStream_t stream) {
  const float* hs     = (const float*)d_in[0];
  const float* wqkv   = (const float*)d_in[1];
  const float* bqkv   = (const float*)d_in[2];
  const float* wdense = (const float*)d_in[3];
  const float* rope   = (const float*)d_in[4];
  char* ws = (char*)d_ws;
  u16* hid_b = (u16*)(ws + 0);
  u16* w_b   = (u16*)(ws + 16777216);
  u16* qb    = (u16*)(ws + 54525952);
  u16* kb    = (u16*)(ws + 71303168);
  u16* vtb   = (u16*)(ws + 72351744);
  u16* ctx   = hid_b;                      // reuse after GEMM1
  float* outf = (float*)d_out;

  k_cvt<<<2048, 256, 0, stream>>>(hs,   hid_b, SQL * HID / 8);
  k_cvt<<<2048, 256, 0, stream>>>(wqkv, w_b,   QKVD * HID / 8);
  k_gemm<0><<<dim3(QKVD / 128, SQL / 128), 256, 0, stream>>>(
      hid_b, w_b, bqkv, qb, kb, vtb, nullptr);
  k_rope<<<(SQL * 34 * 32) / 256, 256, 0, stream>>>(qb, kb, rope);
  k_cvt<<<2048, 256, 0, stream>>>(wdense, w_b, QDIM * HID / 8);   // after GEMM1
  k_attn<<<dim3(NHEADS, SQL / 16), 64, 0, stream>>>(qb, kb, vtb, ctx);
  k_gemm<1><<<dim3(QDIM / 128, SQL / 128), 256, 0, stream>>>(
      ctx, w_b, nullptr, nullptr, nullptr, nullptr, outf);
}

// Round 4
// 338.418 us; speedup vs baseline: 2.1188x; 1.3442x over previous
//
#include <hip/hip_runtime.h>
#include <stdint.h>

#define SQL 2048
#define HID 4096
#define NHEADS 32
#define HDSZ 128
#define QKVD 4608
#define QDIM 4096

typedef unsigned short u16;
typedef __attribute__((ext_vector_type(8))) short short8;
typedef __attribute__((ext_vector_type(4))) float f32x4;

#define AS1(p) ((__attribute__((address_space(1))) void*)(p))
#define AS3(p) ((__attribute__((address_space(3))) void*)(p))

__device__ __forceinline__ float bf2f(u16 u) {
  return __uint_as_float(((uint32_t)u) << 16);
}
__device__ __forceinline__ u16 f2bf(float f) {
  uint32_t x = __float_as_uint(f);
  x += 0x7fffu + ((x >> 16) & 1u);
  return (u16)(x >> 16);
}

// ---------- fp32 -> bf16 convert, 8 elems/thread ----------
__global__ void k_cvt(const float* __restrict__ in, u16* __restrict__ out, int n8) {
  int i = blockIdx.x * blockDim.x + threadIdx.x;
  int stride = gridDim.x * blockDim.x;
  for (; i < n8; i += stride) {
    const float4* p = reinterpret_cast<const float4*>(in) + (size_t)i * 2;
    float4 a = p[0], b = p[1];
    short8 o;
    o[0] = (short)f2bf(a.x); o[1] = (short)f2bf(a.y);
    o[2] = (short)f2bf(a.z); o[3] = (short)f2bf(a.w);
    o[4] = (short)f2bf(b.x); o[5] = (short)f2bf(b.y);
    o[6] = (short)f2bf(b.z); o[7] = (short)f2bf(b.w);
    reinterpret_cast<short8*>(out)[i] = o;
  }
}

// ---------- GEMM C[M][N] = A[M][K] * B[N][K]^T, bf16 MFMA ----------
// MODE 0: qkv epilogue (bias + scatter to q/k/vt).  MODE 1: fp32 C store.
template<int MODE>
__global__ __launch_bounds__(256, 2)
void k_gemm(const u16* __restrict__ A, const u16* __restrict__ B,
            const float* __restrict__ bias,
            u16* __restrict__ qbuf, u16* __restrict__ kbuf, u16* __restrict__ vtbuf,
            float* __restrict__ outf)
{
  __shared__ __align__(16) u16 ldsA[128 * 64];
  __shared__ __align__(16) u16 ldsB[128 * 64];
  const int tid = threadIdx.x;
  const int wid = tid >> 6, lane = tid & 63;
  const int l15 = lane & 15, lg = lane >> 4;
  const int m0 = blockIdx.y * 128, n0 = blockIdx.x * 128;
  const int wr = wid >> 1, wc = wid & 1;

  f32x4 acc[4][4] = {};

  const int srow = lane >> 3;                      // row within 8-row segment
  const int skb  = (((lane & 7) ^ srow) << 4);     // pre-swizzled source byte
  const size_t rowbytes = (size_t)HID * 2;

  for (int t = 0; t < HID / 64; ++t) {
    __syncthreads();
    const char* Ab = (const char*)A + (size_t)m0 * rowbytes + (size_t)t * 128;
    const char* Bb = (const char*)B + (size_t)n0 * rowbytes + (size_t)t * 128;
#pragma unroll
    for (int i = 0; i < 4; ++i) {
      int seg = i * 4 + wid;
      int row = seg * 8 + srow;
      __builtin_amdgcn_global_load_lds(AS1(Ab + (size_t)row * rowbytes + skb),
                                       AS3(ldsA + seg * 512), 16, 0, 0);
      __builtin_amdgcn_global_load_lds(AS1(Bb + (size_t)row * rowbytes + skb),
                                       AS3(ldsB + seg * 512), 16, 0, 0);
    }
    __syncthreads();
#pragma unroll
    for (int kc = 0; kc < 2; ++kc) {
      short8 af[4], bfr[4];
#pragma unroll
      for (int mi = 0; mi < 4; ++mi) {
        int row = wr * 64 + mi * 16 + l15;
        int kb = (kc * 64 + lg * 16) ^ ((row & 7) << 4);
        af[mi] = *reinterpret_cast<const short8*>((const char*)ldsA + row * 128 + kb);
      }
#pragma unroll
      for (int ni = 0; ni < 4; ++ni) {
        int row = wc * 64 + ni * 16 + l15;
        int kb = (kc * 64 + lg * 16) ^ ((row & 7) << 4);
        bfr[ni] = *reinterpret_cast<const short8*>((const char*)ldsB + row * 128 + kb);
      }
#pragma unroll
      for (int mi = 0; mi < 4; ++mi)
#pragma unroll
        for (int ni = 0; ni < 4; ++ni)
          acc[mi][ni] = __builtin_amdgcn_mfma_f32_16x16x32_bf16(af[mi], bfr[ni], acc[mi][ni], 0, 0, 0);
    }
  }

#pragma unroll
  for (int mi = 0; mi < 4; ++mi) {
#pragma unroll
    for (int ni = 0; ni < 4; ++ni) {
      int row0 = m0 + wr * 64 + mi * 16 + lg * 4;
      int col  = n0 + wc * 64 + ni * 16 + l15;
      if (MODE == 0) {
        float bv = bias[col];
#pragma unroll
        for (int j = 0; j < 4; ++j) {
          float v = acc[mi][ni][j] + bv;
          u16 hb = f2bf(v);
          int r = row0 + j;
          if (col < QDIM) {
            int hh = col >> 7, d = col & 127;
            qbuf[((size_t)hh * SQL + r) * HDSZ + d] = hb;
          } else if (col < QDIM + 256) {
            int c2 = col - QDIM; int g = c2 >> 7, d = c2 & 127;
            kbuf[((size_t)g * SQL + r) * HDSZ + d] = hb;
          } else {
            int c2 = col - QDIM - 256; int g = c2 >> 7, d = c2 & 127;
            vtbuf[((size_t)g * HDSZ + d) * SQL + r] = hb;   // V stored transposed
          }
        }
      } else {
#pragma unroll
        for (int j = 0; j < 4; ++j)
          outf[(size_t)(row0 + j) * QDIM + col] = acc[mi][ni][j];
      }
    }
  }
}

// ---------- RoPE (interleaved pairs, first 64 dims), in place on q and k ----------
__global__ void k_rope(u16* __restrict__ qbuf, u16* __restrict__ kbuf,
                       const float* __restrict__ rope) {
  int idx = blockIdx.x * blockDim.x + threadIdx.x;
  if (idx >= SQL * 34 * 32) return;
  int p = idx & 31;
  int hh = (idx >> 5) % 34;
  int s = idx / (34 * 32);
  float c  = rope[s * 64 + p * 2 + 0];
  float sn = rope[s * 64 + p * 2 + 1];
  u16* base = (hh < 32) ? (qbuf + ((size_t)hh * SQL + s) * HDSZ)
                        : (kbuf + ((size_t)(hh - 32) * SQL + s) * HDSZ);
  u16* pp = base + 2 * p;
  uint32_t packed = *reinterpret_cast<uint32_t*>(pp);
  float x0 = bf2f((u16)(packed & 0xffff));
  float x1 = bf2f((u16)(packed >> 16));
  float o0 = x0 * c - x1 * sn;
  float o1 = x1 * c + x0 * sn;
  *reinterpret_cast<uint32_t*>(pp) = (uint32_t)f2bf(o0) | ((uint32_t)f2bf(o1) << 16);
}

// ---------- flash attention: causal, GQA (g = h>>4), online softmax ----------
// ONE wave per block, QBLK=32 q-rows (2 row-tiles), KVBLK=64.
//  - 32 rows/wave halves KV L2 traffic per unit work vs 16 (arith intensity).
//  - KVBLK=64 amortizes the two 4-shfl reduce chains over 4 kv-subtiles
//    (extra reduction is in-register fmax/add).
//  - V loads are issued BEFORE the softmax chain (source order, ahead of the
//    asm memory clobber) so L2 latency hides under softmax VALU work.
// grid = (NHEADS, SQL/32), qi reversed for global LPT ordering.
__global__ __launch_bounds__(64)
void k_attn(const u16* __restrict__ qbuf, const u16* __restrict__ kbuf,
            const u16* __restrict__ vtbuf, u16* __restrict__ ctx)
{
  __shared__ __align__(16) u16 pls[32 * 72];   // P tile [32 rows][64 kv + 8 pad]
  const int lane = threadIdx.x;
  const int l15 = lane & 15, lg = lane >> 4;
  const int h = blockIdx.x;
  const int g = h >> 4;                     // n_rep = 16
  const int qi = (int)gridDim.y - 1 - (int)blockIdx.y;
  const int q0 = qi * 32;
  const float inv_norm = 0.08838834764831845f;   // 1/sqrt(128)

  short8 aq[2][4];
#pragma unroll
  for (int rt = 0; rt < 2; ++rt) {
    const u16* qp = qbuf + ((size_t)h * SQL + q0 + rt * 16 + l15) * HDSZ + lg * 8;
#pragma unroll
    for (int kc = 0; kc < 4; ++kc)
      aq[rt][kc] = *reinterpret_cast<const short8*>(qp + kc * 32);
  }
  f32x4 o[2][8] = {};
  float mrow[2][4], lrow[2][4];
#pragma unroll
  for (int rt = 0; rt < 2; ++rt)
#pragma unroll
    for (int j = 0; j < 4; ++j) { mrow[rt][j] = -__builtin_inff(); lrow[rt][j] = 0.f; }

  const int jend = q0 + 31;
  for (int j0 = 0; j0 <= jend; j0 += 64) {
    // K tile: 4 kv-subtiles x 4 k-chunks
    short8 bk[4][4];
    const u16* kp = kbuf + ((size_t)g * SQL + j0 + l15) * HDSZ + lg * 8;
#pragma unroll
    for (int kt = 0; kt < 4; ++kt)
#pragma unroll
      for (int kc = 0; kc < 4; ++kc)
        bk[kt][kc] = *reinterpret_cast<const short8*>(kp + (size_t)kt * 16 * HDSZ + kc * 32);

    f32x4 s[2][4] = {};
    __builtin_amdgcn_s_setprio(1);
#pragma unroll
    for (int kc = 0; kc < 4; ++kc)
#pragma unroll
      for (int rt = 0; rt < 2; ++rt)
#pragma unroll
        for (int kt = 0; kt < 4; ++kt)
          s[rt][kt] = __builtin_amdgcn_mfma_f32_16x16x32_bf16(aq[rt][kc], bk[kt][kc], s[rt][kt], 0, 0, 0);
    __builtin_amdgcn_s_setprio(0);

    // V loads issued early: consumed only at PV, latency hides under softmax
    short8 bv[8][2];
    const u16* vp = vtbuf + ((size_t)g * HDSZ + l15) * SQL + j0 + lg * 8;
#pragma unroll
    for (int df = 0; df < 8; ++df)
#pragma unroll
      for (int kc2 = 0; kc2 < 2; ++kc2)
        bv[df][kc2] = *reinterpret_cast<const short8*>(vp + (size_t)df * 16 * SQL + kc2 * 32);

    // softmax: 8 independent chains (rt, j)
    float al[2][4];
#pragma unroll
    for (int rt = 0; rt < 2; ++rt) {
#pragma unroll
      for (int j = 0; j < 4; ++j) {
        int row = q0 + rt * 16 + lg * 4 + j;
        float v[4];
#pragma unroll
        for (int kt = 0; kt < 4; ++kt) {
          float sv = s[rt][kt][j] * inv_norm;
          v[kt] = (j0 + kt * 16 + l15 > row) ? -1e30f : sv;
        }
        float rm = fmaxf(fmaxf(v[0], v[1]), fmaxf(v[2], v[3]));
        rm = fmaxf(rm, __shfl_xor(rm, 1));
        rm = fmaxf(rm, __shfl_xor(rm, 2));
        rm = fmaxf(rm, __shfl_xor(rm, 4));
        rm = fmaxf(rm, __shfl_xor(rm, 8));
        float mn = fmaxf(mrow[rt][j], rm);
        float a = __expf(mrow[rt][j] - mn);     // first tile: exp(-inf)=0
        mrow[rt][j] = mn;
        float p[4], ps = 0.f;
#pragma unroll
        for (int kt = 0; kt < 4; ++kt) { p[kt] = __expf(v[kt] - mn); ps += p[kt]; }
        ps += __shfl_xor(ps, 1);
        ps += __shfl_xor(ps, 2);
        ps += __shfl_xor(ps, 4);
        ps += __shfl_xor(ps, 8);
        lrow[rt][j] = lrow[rt][j] * a + ps;
        al[rt][j] = a;
        int rl = rt * 16 + lg * 4 + j;
#pragma unroll
        for (int kt = 0; kt < 4; ++kt)
          pls[rl * 72 + kt * 16 + l15] = f2bf(p[kt]);
      }
    }
    asm volatile("s_waitcnt lgkmcnt(0)" ::: "memory");  // wave-local P write->read

    short8 ap[2][2];
#pragma unroll
    for (int rt = 0; rt < 2; ++rt)
#pragma unroll
      for (int kc2 = 0; kc2 < 2; ++kc2)
        ap[rt][kc2] = *reinterpret_cast<const short8*>(&pls[(rt * 16 + l15) * 72 + kc2 * 32 + lg * 8]);

    __builtin_amdgcn_s_setprio(1);
#pragma unroll
    for (int rt = 0; rt < 2; ++rt) {
#pragma unroll
      for (int df = 0; df < 8; ++df) {
        f32x4 t = o[rt][df];
        t[0] *= al[rt][0]; t[1] *= al[rt][1]; t[2] *= al[rt][2]; t[3] *= al[rt][3];
        t = __builtin_amdgcn_mfma_f32_16x16x32_bf16(ap[rt][0], bv[df][0], t, 0, 0, 0);
        t = __builtin_amdgcn_mfma_f32_16x16x32_bf16(ap[rt][1], bv[df][1], t, 0, 0, 0);
        o[rt][df] = t;
      }
    }
    __builtin_amdgcn_s_setprio(0);
  }

#pragma unroll
  for (int rt = 0; rt < 2; ++rt) {
#pragma unroll
    for (int j = 0; j < 4; ++j) {
      float inv_l = 1.0f / lrow[rt][j];
      int row = q0 + rt * 16 + lg * 4 + j;
      u16* cp = ctx + (size_t)row * QDIM + h * HDSZ;
#pragma unroll
      for (int df = 0; df < 8; ++df)
        cp[df * 16 + l15] = f2bf(o[rt][df][j] * inv_l);
    }
  }
}

// ---------- workspace layout (bytes) ----------
//  0        : hidden_bf16 [2048][4096]   16777216   (reused as ctx after GEMM1)
//  16777216 : W_bf16      [4608][4096]   37748736   (Wqkv, then Wdense)
//  54525952 : q           [32][2048][128] 16777216
//  71303168 : k           [2][2048][128]   1048576
//  72351744 : vt          [2][128][2048]   1048576
//  total 73400320

extern "C" void kernel_launch(void* const* d_in, const int* in_sizes, int n_in,
                              void* d_out, int out_size, void* d_ws, size_t ws_size,
                              hipStream_t stream) {
  const float* hs     = (const float*)d_in[0];
  const float* wqkv   = (const float*)d_in[1];
  const float* bqkv   = (const float*)d_in[2];
  const float* wdense = (const float*)d_in[3];
  const float* rope   = (const float*)d_in[4];
  char* ws = (char*)d_ws;
  u16* hid_b = (u16*)(ws + 0);
  u16* w_b   = (u16*)(ws + 16777216);
  u16* qb    = (u16*)(ws + 54525952);
  u16* kb    = (u16*)(ws + 71303168);
  u16* vtb   = (u16*)(ws + 72351744);
  u16* ctx   = hid_b;                      // reuse after GEMM1
  float* outf = (float*)d_out;

  k_cvt<<<2048, 256, 0, stream>>>(hs,   hid_b, SQL * HID / 8);
  k_cvt<<<2048, 256, 0, stream>>>(wqkv, w_b,   QKVD * HID / 8);
  k_gemm<0><<<dim3(QKVD / 128, SQL / 128), 256, 0, stream>>>(
      hid_b, w_b, bqkv, qb, kb, vtb, nullptr);
  k_rope<<<(SQL * 34 * 32) / 256, 256, 0, stream>>>(qb, kb, rope);
  k_cvt<<<2048, 256, 0, stream>>>(wdense, w_b, QDIM * HID / 8);   // after GEMM1
  k_attn<<<dim3(NHEADS, SQL / 32), 64, 0, stream>>>(qb, kb, vtb, ctx);
  k_gemm<1><<<dim3(QDIM / 128, SQL / 128), 256, 0, stream>>>(
      ctx, w_b, nullptr, nullptr, nullptr, nullptr, outf);
}